// Round 4
// baseline (7966.688 us; speedup 1.0000x reference)
//
#include <hip/hip_runtime.h>
#include <cstddef>
#include <cstdint>

typedef unsigned long long ull;
typedef unsigned short u16;
typedef __attribute__((ext_vector_type(8))) short s8v;   // 8 x bf16 (MFMA A/B frag)
typedef __attribute__((ext_vector_type(4))) float f4v;   // MFMA C/D frag

#define GROUPS 8
#define WPG    32
#define BG     16
#define JS     16
#define TPB    256
#define NT     1024
#define HDIM   512
#define INDIM  17
#define OUTDIM 17
#define BTOT   128
#define RING_D 4

// Cross-WG traffic: relaxed agent-scope atomics (sc1 -> MALL). No fences.
#define AT_LD(p)   __hip_atomic_load((p), __ATOMIC_RELAXED, __HIP_MEMORY_SCOPE_AGENT)
#define AT_ST(p,v) __hip_atomic_store((p), (v), __ATOMIC_RELAXED, __HIP_MEMORY_SCOPE_AGENT)

// ---------------- workspace ----------------
#define FLAGS_INTS (256 * 16)
#define RING_OFF   ((size_t)FLAGS_INTS * 4)
#define RING_ELEMS ((size_t)RING_D * GROUPS * 2 * BG * HDIM)   // h0 ring (hi/lo planes)
#define H1_OFF     (RING_OFF + RING_ELEMS * 2)
#define H1_ELEMS   ((size_t)2 * GROUPS * 2 * BG * HDIM)        // h1 double buffer
#define WS_NEEDED  (H1_OFF + H1_ELEMS * 2)                     // ~1.6 MB

#define RIDX(sl, gr, pl, b, j) \
  (((((size_t)(sl) * GROUPS + (gr)) * 2 + (pl)) * BG + (b)) * HDIM + (j))
#define H1IDX(pp, gr, pl, b, j) \
  (((((size_t)(pp) * GROUPS + (gr)) * 2 + (pl)) * BG + (b)) * HDIM + (j))

// ---------------- helpers ----------------
__device__ __forceinline__ u16 f2bf(float f) {
  unsigned int u = __float_as_uint(f);
  u += 0x7FFFu + ((u >> 16) & 1u);
  return (u16)(u >> 16);
}
__device__ __forceinline__ float bf2f(u16 h) {
  return __uint_as_float(((unsigned int)h) << 16);
}
__device__ __forceinline__ float sigm(float x) { return 1.f / (1.f + __expf(-x)); }
__device__ __forceinline__ float tanh_f(float x) { return 2.f / (1.f + __expf(-2.f * x)) - 1.f; }

#define MFMA(a, b, c) __builtin_amdgcn_mfma_f32_16x16x32_bf16((a), (b), (c), 0, 0, 0)

__device__ __forceinline__ s8v ld16(const ull* p) {   // 16B via two 8B MALL atomics
  union { ull q[2]; s8v v; } u;
  u.q[0] = AT_LD(p);
  u.q[1] = AT_LD(p + 1);
  return u.v;
}

// ---------------- fused 2-layer persistent LSTM (K-split waves) ----------------
// 256 WGs (1/CU). Group gr = bid&7 owns batches [gr*16,gr*16+16); WG wg = bid>>3
// owns j-slice [wg*16,wg*16+16) for both layers.
// Wave w owns k-quarter [w*128,(w+1)*128) and holds ALL 4 gates' B-frags for it.
// Per step each wave loads its DISTINCT A k-quarter straight from MALL into
// registers (no LDS staging); partial gate pre-acts reduced across waves via a
// 32 KB swizzled LDS exchange. Super-step s: L0 step s, L1 step s-1.
__global__ __launch_bounds__(TPB, 1) void lstm_fused(
    const float* __restrict__ x,
    const float* __restrict__ wih0, const float* __restrict__ whh0,
    const float* __restrict__ bih0, const float* __restrict__ bhh0,
    const float* __restrict__ wih1, const float* __restrict__ whh1,
    const float* __restrict__ bih1, const float* __restrict__ bhh1,
    u16* __restrict__ ring,   // h0 ring [slot4][gr][pl2][b16][j512]
    u16* __restrict__ h1b,    // h1 dbuf [pp2][gr][pl2][b16][j512]
    int* __restrict__ flags)
{
  const int bid  = blockIdx.x;
  const int gr   = bid & 7;
  const int wg   = bid >> 3;
  const int j0   = wg * JS;
  const int tid  = threadIdx.x;
  const int wave = tid >> 6;
  const int lane = tid & 63;
  const int n    = lane & 15;        // A-frag row (batch) / B-frag col (j)
  const int q    = lane >> 4;        // k-sub-quad within a 32-tile
  const int k0   = q * 8;
  const int kw   = wave * 128;       // this wave's k-quarter base

  __shared__ float red[4 * 8 * 16 * 16];   // [wave][lg8][col16][row16] partials, 32 KB

  // ---- stationary weights: per wave, 4 gates x 4 k-tiles of its quarter ----
  // w0x (L0 x-part, K=17): gate = wave, full padded tile (redundant across waves)
  s8v w0x_h, w0x_l;
  {
    const float* wr = wih0 + (size_t)(wave * HDIM + j0 + n) * INDIM;
#pragma unroll
    for (int j = 0; j < 8; ++j) {
      int k = k0 + j;
      float v = (k < INDIM) ? wr[k] : 0.f;
      u16 hi = f2bf(v);
      w0x_h[j] = (short)hi;
      w0x_l[j] = (short)f2bf(v - bf2f(hi));
    }
  }
  s8v w0hh[4][4], w0hl[4][4], w1xh[4][4], w1hh[4][4], w1hl[4][4];  // [gate][kt]
#pragma unroll
  for (int g = 0; g < 4; ++g) {
    const size_t row = (size_t)(g * HDIM + j0 + n);
    const float* p0 = whh0 + row * HDIM;
    const float* p1 = wih1 + row * HDIM;
    const float* p2 = whh1 + row * HDIM;
#pragma unroll
    for (int kt = 0; kt < 4; ++kt) {
#pragma unroll
      for (int j = 0; j < 8; ++j) {
        int k = kw + kt * 32 + k0 + j;
        float v0 = p0[k], v2 = p2[k];
        u16 h0q = f2bf(v0), h2q = f2bf(v2);
        w0hh[g][kt][j] = (short)h0q;
        w0hl[g][kt][j] = (short)f2bf(v0 - bf2f(h0q));
        w1xh[g][kt][j] = (short)f2bf(p1[k]);
        w1hh[g][kt][j] = (short)h2q;
        w1hl[g][kt][j] = (short)f2bf(v2 - bf2f(h2q));
      }
    }
  }
  // per-thread biases for the elementwise phase (thread -> b=tid>>4, j=tid&15)
  const int b_l = tid >> 4, j_l = tid & 15, jg = j0 + j_l;
  float bL0[4], bL1[4];
#pragma unroll
  for (int g = 0; g < 4; ++g) {
    bL0[g] = bih0[g * HDIM + jg] + bhh0[g * HDIM + jg];
    bL1[g] = bih1[g * HDIM + jg] + bhh1[g * HDIM + jg];
  }

  float c0 = 0.f, c1 = 0.f;

  // ---- init h0 ring slot0 = 0, h1 parity0 = 0 ----
  AT_ST(&ring[RIDX(0, gr, 0, b_l, jg)], (u16)0);
  AT_ST(&ring[RIDX(0, gr, 1, b_l, jg)], (u16)0);
  AT_ST(&h1b[H1IDX(0, gr, 0, b_l, jg)], (u16)0);
  AT_ST(&h1b[H1IDX(0, gr, 1, b_l, jg)], (u16)0);
  __syncthreads();
  if (tid == 0) AT_ST(&flags[bid * 16], 1);

  const f4v z = {0.f, 0.f, 0.f, 0.f};

  for (int s = 1; s <= NT + 1; ++s) {
    const bool doL0 = (s <= NT);
    const bool doL1 = (s >= 2);

    // L0 x-part for gate `wave` (no peer dependency): before the wait
    f4v xacc = z;
    if (doL0) {
      const int t = s - 1;
      const float* xr = x + ((size_t)(gr * BG + n) * NT + t) * INDIM;
      s8v axh, axl;
#pragma unroll
      for (int j = 0; j < 8; ++j) {
        int k = k0 + j;
        float v = (k < INDIM) ? xr[k] : 0.f;
        u16 hi = f2bf(v);
        axh[j] = (short)hi;
        axl[j] = (short)f2bf(v - bf2f(hi));
      }
      xacc = MFMA(axh, w0x_h, xacc);
      xacc = MFMA(axl, w0x_h, xacc);
      xacc = MFMA(axh, w0x_l, xacc);
    }

    // wait: all 32 group peers published step s-1
    if (tid < WPG) {
      const int* fp = &flags[(tid * 8 + gr) * 16];
      while (AT_LD(fp) < s) __builtin_amdgcn_s_sleep(1);
    }
    __syncthreads();   // [B1]

    // ---- A-loads: this wave's k-quarter of h0[s-1] and h1[s-2], MALL->regs ----
    const int sl  = (s - 1) & (RING_D - 1);
    const int pp1 = s & 1;
    const size_t loff = (size_t)n * HDIM + kw + k0;
    const ull* r0h = (const ull*)(ring + RIDX(sl, gr, 0, 0, 0) + loff);
    const ull* r0l = (const ull*)(ring + RIDX(sl, gr, 1, 0, 0) + loff);
    const ull* r1h = (const ull*)(h1b + H1IDX(pp1, gr, 0, 0, 0) + loff);
    const ull* r1l = (const ull*)(h1b + H1IDX(pp1, gr, 1, 0, 0) + loff);
    s8v a0h[4], a0l[4], a1h[4], a1l[4];
#pragma unroll
    for (int kt = 0; kt < 4; ++kt) {   // kt stride = 32 u16 = 8 ull
      a0h[kt] = ld16(r0h + kt * 8);
      a0l[kt] = ld16(r0l + kt * 8);
    }
#pragma unroll
    for (int kt = 0; kt < 4; ++kt) {
      a1h[kt] = ld16(r1h + kt * 8);
      a1l[kt] = ld16(r1l + kt * 8);
    }

    // ---- MFMA: partial gate pre-acts over this k-quarter, all 4 gates ----
    f4v accL0[4] = {z, z, z, z}, accL1[4] = {z, z, z, z};
#pragma unroll
    for (int kt = 0; kt < 4; ++kt)
#pragma unroll
      for (int g = 0; g < 4; ++g) {
        accL0[g] = MFMA(a0h[kt], w0hh[g][kt], accL0[g]);
        accL0[g] = MFMA(a0l[kt], w0hh[g][kt], accL0[g]);
        accL0[g] = MFMA(a0h[kt], w0hl[g][kt], accL0[g]);
        accL1[g] = MFMA(a0h[kt], w1xh[g][kt], accL1[g]);   // L1 x-part: y0 = h0[s-2]... same tile
        accL1[g] = MFMA(a0l[kt], w1xh[g][kt], accL1[g]);
      }
#pragma unroll
    for (int kt = 0; kt < 4; ++kt)
#pragma unroll
      for (int g = 0; g < 4; ++g) {
        accL1[g] = MFMA(a1h[kt], w1hh[g][kt], accL1[g]);
        accL1[g] = MFMA(a1l[kt], w1hh[g][kt], accL1[g]);
        accL1[g] = MFMA(a1h[kt], w1hl[g][kt], accL1[g]);
      }
    accL0[wave] += xacc;   // fold x-part (gate == wave) into this wave's partial

    // ---- write partials: [wave][lg][col n][row16], XOR-swizzled, b128 ----
#pragma unroll
    for (int lg = 0; lg < 8; ++lg) {
      const f4v a = (lg < 4) ? accL0[lg] : accL1[lg - 4];
      int base = ((wave * 8 + lg) * 16 + n) * 16;
      int idx = (base + ((q * 4) ^ ((n & 3) << 2))) ^ ((n & 4) << 2);
      *(f4v*)&red[idx] = a;
    }
    __syncthreads();   // [B2]

    // ---- reduce 4 wave-partials + bias, elementwise update ----
    if (doL0) {
      float p[4];
#pragma unroll
      for (int g = 0; g < 4; ++g) {
        float t = bL0[g];
#pragma unroll
        for (int w = 0; w < 4; ++w) {
          int base = ((w * 8 + g) * 16 + j_l) * 16;
          int idx = (base + (b_l ^ ((j_l & 3) << 2))) ^ ((j_l & 4) << 2);
          t += red[idx];
        }
        p[g] = t;
      }
      float ig = sigm(p[0]), fg = sigm(p[1]), og = sigm(p[3]), gg = tanh_f(p[2]);
      c0 = fg * c0 + ig * gg;
      float h = og * tanh_f(c0);
      u16 hh = f2bf(h), hl = f2bf(h - bf2f(hh));
      int so = s & (RING_D - 1);
      AT_ST(&ring[RIDX(so, gr, 0, b_l, jg)], hh);
      AT_ST(&ring[RIDX(so, gr, 1, b_l, jg)], hl);
    }
    if (doL1) {
      float p[4];
#pragma unroll
      for (int g = 0; g < 4; ++g) {
        float t = bL1[g];
#pragma unroll
        for (int w = 0; w < 4; ++w) {
          int base = ((w * 8 + (4 + g)) * 16 + j_l) * 16;
          int idx = (base + (b_l ^ ((j_l & 3) << 2))) ^ ((j_l & 4) << 2);
          t += red[idx];
        }
        p[g] = t;
      }
      float ig = sigm(p[0]), fg = sigm(p[1]), og = sigm(p[3]), gg = tanh_f(p[2]);
      c1 = fg * c1 + ig * gg;
      float h = og * tanh_f(c1);
      u16 hh = f2bf(h), hl = f2bf(h - bf2f(hh));
      int pw = (s - 1) & 1;
      AT_ST(&h1b[H1IDX(pw, gr, 0, b_l, jg)], hh);
      AT_ST(&h1b[H1IDX(pw, gr, 1, b_l, jg)], hl);
    }
    __syncthreads();   // [B3] drains h stores (vmcnt 0) + guards red[] reuse
    if (doL0 && tid == 0) AT_ST(&flags[bid * 16], s + 1);
  }
}

// ---------------- final linear: out = h1[NT] @ lin_w^T + lin_b ----------------
__global__ void final_linear(const u16* __restrict__ h1b,
                             const float* __restrict__ lin_w,
                             const float* __restrict__ lin_b,
                             float* __restrict__ out) {
  int b = blockIdx.x, o = threadIdx.x;
  int gr = b >> 4, b_l = b & 15;
  if (o < OUTDIM) {
    float acc = lin_b[o];
    const u16* ph = h1b + H1IDX(0, gr, 0, b_l, 0);  // h1[1024]: parity 0
    const u16* pl = h1b + H1IDX(0, gr, 1, b_l, 0);
    for (int j = 0; j < HDIM; ++j) {
      float h = bf2f(ph[j]) + bf2f(pl[j]);
      acc += h * lin_w[(size_t)o * HDIM + j];
    }
    out[b * OUTDIM + o] = acc;
  }
}

__global__ void init_flags(int* __restrict__ flags) {
  int i = blockIdx.x * TPB + threadIdx.x;
  if (i < FLAGS_INTS) flags[i] = 0;
}

__global__ void sentinel_kernel(float* __restrict__ out, int nv) {
  int i = blockIdx.x * TPB + threadIdx.x;
  if (i < nv) out[i] = 1e30f;
}

extern "C" void kernel_launch(void* const* d_in, const int* in_sizes, int n_in,
                              void* d_out, int out_size, void* d_ws, size_t ws_size,
                              hipStream_t stream) {
  const float* x     = (const float*)d_in[0];
  const float* wih0  = (const float*)d_in[1];
  const float* whh0  = (const float*)d_in[2];
  const float* bih0  = (const float*)d_in[3];
  const float* bhh0  = (const float*)d_in[4];
  const float* wih1  = (const float*)d_in[5];
  const float* whh1  = (const float*)d_in[6];
  const float* bih1  = (const float*)d_in[7];
  const float* bhh1  = (const float*)d_in[8];
  const float* lin_w = (const float*)d_in[9];
  const float* lin_b = (const float*)d_in[10];
  float* out = (float*)d_out;
  char* ws = (char*)d_ws;

  if (ws_size < WS_NEEDED) {
    sentinel_kernel<<<(out_size + TPB - 1) / TPB, TPB, 0, stream>>>(out, out_size);
    return;
  }

  int* flags = (int*)ws;
  u16* ring  = (u16*)(ws + RING_OFF);
  u16* h1b   = (u16*)(ws + H1_OFF);

  init_flags<<<(FLAGS_INTS + TPB - 1) / TPB, TPB, 0, stream>>>(flags);
  lstm_fused<<<256, TPB, 0, stream>>>(x, wih0, whh0, bih0, bhh0,
                                      wih1, whh1, bih1, bhh1, ring, h1b, flags);
  final_linear<<<BTOT, 64, 0, stream>>>(h1b, lin_w, lin_b, out);
}

// Round 5
// 7641.633 us; speedup vs baseline: 1.0425x; 1.0425x over previous
//
#include <hip/hip_runtime.h>
#include <cstddef>
#include <cstdint>

typedef unsigned long long ull;
typedef unsigned short u16;
typedef __attribute__((ext_vector_type(8))) short s8v;   // 8 x bf16 (MFMA A/B frag)
typedef __attribute__((ext_vector_type(4))) float f4v;   // MFMA C/D frag

#define GROUPS 8
#define WPG    32
#define BG     16
#define JS     16
#define TPB    256
#define NT     1024
#define HDIM   512
#define INDIM  17
#define OUTDIM 17
#define BTOT   128
#define RING_D 4

// Cross-WG traffic: relaxed agent-scope atomics (sc1 -> MALL). No fences.
#define AT_LD(p)   __hip_atomic_load((p), __ATOMIC_RELAXED, __HIP_MEMORY_SCOPE_AGENT)
#define AT_ST(p,v) __hip_atomic_store((p), (v), __ATOMIC_RELAXED, __HIP_MEMORY_SCOPE_AGENT)

// ---------------- frag-order tile layout ----------------
// Group tile (one plane) = 16 b x 512 k stored so that MFMA A-frag loads are
// contiguous: u16 idx(k, b) = (k>>5)*512 + ((k>>3)&3)*128 + b*8 + (k&7).
// Wave w, lane (q,n), k-tile kt reads 16B at (w*4+kt)*512 + q*128 + n*8
// -> 64 lanes = contiguous 1KB burst per kt. 8192 u16 per plane.
#define TILE_U16 8192
#define WIDX(k, b) ((((k) >> 5) * 512) + ((((k) >> 3) & 3) * 128) + ((b) * 8) + ((k) & 7))

// ---------------- workspace ----------------
#define FLAGS_INTS (256 * 16)
#define RING_OFF   ((size_t)FLAGS_INTS * 4)
#define RING_U16   ((size_t)RING_D * GROUPS * 2 * TILE_U16)   // h0 ring, 1 MB
#define H1_OFF     (RING_OFF + RING_U16 * 2)
#define H1_U16     ((size_t)2 * GROUPS * 2 * TILE_U16)        // h1 dbuf, 512 KB
#define WS_NEEDED  (H1_OFF + H1_U16 * 2)                      // ~1.6 MB

#define RIDX2(sl, gr, pl) ((((size_t)(sl) * GROUPS + (gr)) * 2 + (pl)) * TILE_U16)
#define H1IDX2(pp, gr, pl) ((((size_t)(pp) * GROUPS + (gr)) * 2 + (pl)) * TILE_U16)

// ---------------- helpers ----------------
__device__ __forceinline__ u16 f2bf(float f) {
  unsigned int u = __float_as_uint(f);
  u += 0x7FFFu + ((u >> 16) & 1u);
  return (u16)(u >> 16);
}
__device__ __forceinline__ float bf2f(u16 h) {
  return __uint_as_float(((unsigned int)h) << 16);
}
__device__ __forceinline__ float sigm(float x) { return 1.f / (1.f + __expf(-x)); }
__device__ __forceinline__ float tanh_f(float x) { return 2.f / (1.f + __expf(-2.f * x)) - 1.f; }

#define MFMA(a, b, c) __builtin_amdgcn_mfma_f32_16x16x32_bf16((a), (b), (c), 0, 0, 0)

__device__ __forceinline__ s8v ld16(const ull* p) {   // 16B via two 8B MALL atomics
  union { ull q[2]; s8v v; } u;
  u.q[0] = AT_LD(p);
  u.q[1] = AT_LD(p + 1);
  return u.v;
}

// ---------------- fused 2-layer persistent LSTM (K-split, frag-order comm) ----
// 256 WGs (1/CU). Group gr = bid&7 owns batches [gr*16,gr*16+16); WG wg = bid>>3
// owns j-slice [wg*16,wg*16+16) for both layers.
// Wave w owns k-quarter [w*128,(w+1)*128), holds all 4 gates' B-frags for it,
// and loads its A k-quarter straight from MALL (frag-order -> coalesced 1KB
// bursts). Partials reduced via 32KB LDS exchange. Super-step s: L0 s, L1 s-1.
__global__ __launch_bounds__(TPB, 1) void lstm_fused(
    const float* __restrict__ x,
    const float* __restrict__ wih0, const float* __restrict__ whh0,
    const float* __restrict__ bih0, const float* __restrict__ bhh0,
    const float* __restrict__ wih1, const float* __restrict__ whh1,
    const float* __restrict__ bih1, const float* __restrict__ bhh1,
    u16* __restrict__ ring,   // h0 ring [slot4][gr][pl2][frag-order 8192]
    u16* __restrict__ h1b,    // h1 dbuf [pp2][gr][pl2][frag-order 8192]
    int* __restrict__ flags)
{
  const int bid  = blockIdx.x;
  const int gr   = bid & 7;
  const int wg   = bid >> 3;
  const int j0   = wg * JS;
  const int tid  = threadIdx.x;
  const int wave = tid >> 6;
  const int lane = tid & 63;
  const int n    = lane & 15;        // A-frag row (batch) / B-frag col (j)
  const int q    = lane >> 4;        // k-sub-quad within a 32-tile
  const int k0   = q * 8;
  const int kw   = wave * 128;       // this wave's k-quarter base

  __shared__ float red[4 * 8 * 16 * 16];   // [wave][lg8][col16][row16], 32 KB

  // ---- stationary weights: per wave, 4 gates x 4 k-tiles of its quarter ----
  s8v w0x_h, w0x_l;   // wih0 (K=17): gate = wave, padded single tile
  {
    const float* wr = wih0 + (size_t)(wave * HDIM + j0 + n) * INDIM;
#pragma unroll
    for (int j = 0; j < 8; ++j) {
      int k = k0 + j;
      float v = (k < INDIM) ? wr[k] : 0.f;
      u16 hi = f2bf(v);
      w0x_h[j] = (short)hi;
      w0x_l[j] = (short)f2bf(v - bf2f(hi));
    }
  }
  s8v w0hh[4][4], w0hl[4][4], w1xh[4][4], w1hh[4][4], w1hl[4][4];  // [gate][kt]
#pragma unroll
  for (int g = 0; g < 4; ++g) {
    const size_t row = (size_t)(g * HDIM + j0 + n);
    const float* p0 = whh0 + row * HDIM;
    const float* p1 = wih1 + row * HDIM;
    const float* p2 = whh1 + row * HDIM;
#pragma unroll
    for (int kt = 0; kt < 4; ++kt) {
#pragma unroll
      for (int j = 0; j < 8; ++j) {
        int k = kw + kt * 32 + k0 + j;
        float v0 = p0[k], v2 = p2[k];
        u16 h0q = f2bf(v0), h2q = f2bf(v2);
        w0hh[g][kt][j] = (short)h0q;
        w0hl[g][kt][j] = (short)f2bf(v0 - bf2f(h0q));
        w1xh[g][kt][j] = (short)f2bf(p1[k]);
        w1hh[g][kt][j] = (short)h2q;
        w1hl[g][kt][j] = (short)f2bf(v2 - bf2f(h2q));
      }
    }
  }
  const int b_l = tid >> 4, j_l = tid & 15, jg = j0 + j_l;
  float bL0[4], bL1[4];
#pragma unroll
  for (int g = 0; g < 4; ++g) {
    bL0[g] = bih0[g * HDIM + jg] + bhh0[g * HDIM + jg];
    bL1[g] = bih1[g * HDIM + jg] + bhh1[g * HDIM + jg];
  }

  float c0 = 0.f, c1 = 0.f;
  const int wofs = WIDX(jg, b_l);   // this thread's h slot in frag-order

  // ---- init h0 ring slot0 = 0, h1 parity0 = 0 (each WG covers its j-slice) ----
  AT_ST(&ring[RIDX2(0, gr, 0) + wofs], (u16)0);
  AT_ST(&ring[RIDX2(0, gr, 1) + wofs], (u16)0);
  AT_ST(&h1b[H1IDX2(0, gr, 0) + wofs], (u16)0);
  AT_ST(&h1b[H1IDX2(0, gr, 1) + wofs], (u16)0);
  __syncthreads();
  if (tid == 0) AT_ST(&flags[bid * 16], 1);

  const f4v z = {0.f, 0.f, 0.f, 0.f};
  const int aoff = wave * 512 + q * 32 + n * 2;   // ull offset of this lane's frag

  for (int s = 1; s <= NT + 1; ++s) {
    const bool doL0 = (s <= NT);
    const bool doL1 = (s >= 2);

    // L0 x-part for gate `wave` (no peer dependency): before the wait
    f4v xacc = z;
    if (doL0) {
      const int t = s - 1;
      const float* xr = x + ((size_t)(gr * BG + n) * NT + t) * INDIM;
      s8v axh, axl;
#pragma unroll
      for (int j = 0; j < 8; ++j) {
        int k = k0 + j;
        float v = (k < INDIM) ? xr[k] : 0.f;
        u16 hi = f2bf(v);
        axh[j] = (short)hi;
        axl[j] = (short)f2bf(v - bf2f(hi));
      }
      xacc = MFMA(axh, w0x_h, xacc);
      xacc = MFMA(axl, w0x_h, xacc);
      xacc = MFMA(axh, w0x_l, xacc);
    }

    // wait: all 32 group peers published step s-1
    if (tid < WPG) {
      const int* fp = &flags[(tid * 8 + gr) * 16];
      while (AT_LD(fp) < s) __builtin_amdgcn_s_sleep(1);
    }
    __syncthreads();   // [B1]

    // ---- A-loads: this wave's k-quarter, MALL->regs, 1KB coalesced bursts ----
    const int sl  = (s - 1) & (RING_D - 1);
    const int pp1 = s & 1;
    const ull* r0h = (const ull*)(ring + RIDX2(sl, gr, 0)) + aoff;
    const ull* r0l = (const ull*)(ring + RIDX2(sl, gr, 1)) + aoff;
    const ull* r1h = (const ull*)(h1b + H1IDX2(pp1, gr, 0)) + aoff;
    const ull* r1l = (const ull*)(h1b + H1IDX2(pp1, gr, 1)) + aoff;
    s8v a0h[4], a0l[4], a1h[4], a1l[4];
#pragma unroll
    for (int kt = 0; kt < 4; ++kt) {   // kt stride = 512 u16 = 128 ull
      a0h[kt] = ld16(r0h + kt * 128);
      a0l[kt] = ld16(r0l + kt * 128);
    }
#pragma unroll
    for (int kt = 0; kt < 4; ++kt) {
      a1h[kt] = ld16(r1h + kt * 128);
      a1l[kt] = ld16(r1l + kt * 128);
    }

    // ---- MFMA: partial gate pre-acts over this k-quarter, all 4 gates ----
    f4v accL0[4] = {z, z, z, z}, accL1[4] = {z, z, z, z};
#pragma unroll
    for (int kt = 0; kt < 4; ++kt)
#pragma unroll
      for (int g = 0; g < 4; ++g) {
        accL0[g] = MFMA(a0h[kt], w0hh[g][kt], accL0[g]);
        accL0[g] = MFMA(a0l[kt], w0hh[g][kt], accL0[g]);
        accL0[g] = MFMA(a0h[kt], w0hl[g][kt], accL0[g]);
        accL1[g] = MFMA(a0h[kt], w1xh[g][kt], accL1[g]);   // L1 x-part shares h0 tile
        accL1[g] = MFMA(a0l[kt], w1xh[g][kt], accL1[g]);
      }
#pragma unroll
    for (int kt = 0; kt < 4; ++kt)
#pragma unroll
      for (int g = 0; g < 4; ++g) {
        accL1[g] = MFMA(a1h[kt], w1hh[g][kt], accL1[g]);
        accL1[g] = MFMA(a1l[kt], w1hh[g][kt], accL1[g]);
        accL1[g] = MFMA(a1h[kt], w1hl[g][kt], accL1[g]);
      }
    accL0[wave] += xacc;

    // ---- write partials: [wave][lg][col n][row16], XOR-swizzled b128 ----
#pragma unroll
    for (int lg = 0; lg < 8; ++lg) {
      const f4v a = (lg < 4) ? accL0[lg] : accL1[lg - 4];
      int base = ((wave * 8 + lg) * 16 + n) * 16;
      int idx = (base + ((q * 4) ^ ((n & 3) << 2))) ^ ((n & 4) << 2);
      *(f4v*)&red[idx] = a;
    }
    __syncthreads();   // [B2]

    // ---- reduce 4 wave-partials + bias, elementwise update ----
    if (doL0) {
      float p[4];
#pragma unroll
      for (int g = 0; g < 4; ++g) {
        float t = bL0[g];
#pragma unroll
        for (int w = 0; w < 4; ++w) {
          int base = ((w * 8 + g) * 16 + j_l) * 16;
          int idx = (base + (b_l ^ ((j_l & 3) << 2))) ^ ((j_l & 4) << 2);
          t += red[idx];
        }
        p[g] = t;
      }
      float ig = sigm(p[0]), fg = sigm(p[1]), og = sigm(p[3]), gg = tanh_f(p[2]);
      c0 = fg * c0 + ig * gg;
      float h = og * tanh_f(c0);
      u16 hh = f2bf(h), hl = f2bf(h - bf2f(hh));
      int so = s & (RING_D - 1);
      AT_ST(&ring[RIDX2(so, gr, 0) + wofs], hh);
      AT_ST(&ring[RIDX2(so, gr, 1) + wofs], hl);
    }
    if (doL1) {
      float p[4];
#pragma unroll
      for (int g = 0; g < 4; ++g) {
        float t = bL1[g];
#pragma unroll
        for (int w = 0; w < 4; ++w) {
          int base = ((w * 8 + (4 + g)) * 16 + j_l) * 16;
          int idx = (base + (b_l ^ ((j_l & 3) << 2))) ^ ((j_l & 4) << 2);
          t += red[idx];
        }
        p[g] = t;
      }
      float ig = sigm(p[0]), fg = sigm(p[1]), og = sigm(p[3]), gg = tanh_f(p[2]);
      c1 = fg * c1 + ig * gg;
      float h = og * tanh_f(c1);
      u16 hh = f2bf(h), hl = f2bf(h - bf2f(hh));
      int pw = (s - 1) & 1;
      AT_ST(&h1b[H1IDX2(pw, gr, 0) + wofs], hh);
      AT_ST(&h1b[H1IDX2(pw, gr, 1) + wofs], hl);
    }
    __syncthreads();   // [B3] drains h stores (vmcnt 0) + guards red[] reuse
    if (doL0 && tid == 0) AT_ST(&flags[bid * 16], s + 1);
  }
}

// ---------------- final linear: out = h1[NT] @ lin_w^T + lin_b ----------------
__global__ void final_linear(const u16* __restrict__ h1b,
                             const float* __restrict__ lin_w,
                             const float* __restrict__ lin_b,
                             float* __restrict__ out) {
  int b = blockIdx.x, o = threadIdx.x;
  int gr = b >> 4, b_l = b & 15;
  if (o < OUTDIM) {
    float acc = lin_b[o];
    const u16* ph = h1b + H1IDX2(0, gr, 0);  // h1[1024]: parity 0
    const u16* pl = h1b + H1IDX2(0, gr, 1);
    for (int j = 0; j < HDIM; ++j) {
      int idx = WIDX(j, b_l);
      float h = bf2f(ph[idx]) + bf2f(pl[idx]);
      acc += h * lin_w[(size_t)o * HDIM + j];
    }
    out[b * OUTDIM + o] = acc;
  }
}

__global__ void init_flags(int* __restrict__ flags) {
  int i = blockIdx.x * TPB + threadIdx.x;
  if (i < FLAGS_INTS) flags[i] = 0;
}

__global__ void sentinel_kernel(float* __restrict__ out, int nv) {
  int i = blockIdx.x * TPB + threadIdx.x;
  if (i < nv) out[i] = 1e30f;
}

extern "C" void kernel_launch(void* const* d_in, const int* in_sizes, int n_in,
                              void* d_out, int out_size, void* d_ws, size_t ws_size,
                              hipStream_t stream) {
  const float* x     = (const float*)d_in[0];
  const float* wih0  = (const float*)d_in[1];
  const float* whh0  = (const float*)d_in[2];
  const float* bih0  = (const float*)d_in[3];
  const float* bhh0  = (const float*)d_in[4];
  const float* wih1  = (const float*)d_in[5];
  const float* whh1  = (const float*)d_in[6];
  const float* bih1  = (const float*)d_in[7];
  const float* bhh1  = (const float*)d_in[8];
  const float* lin_w = (const float*)d_in[9];
  const float* lin_b = (const float*)d_in[10];
  float* out = (float*)d_out;
  char* ws = (char*)d_ws;

  if (ws_size < WS_NEEDED) {
    sentinel_kernel<<<(out_size + TPB - 1) / TPB, TPB, 0, stream>>>(out, out_size);
    return;
  }

  int* flags = (int*)ws;
  u16* ring  = (u16*)(ws + RING_OFF);
  u16* h1b   = (u16*)(ws + H1_OFF);

  init_flags<<<(FLAGS_INTS + TPB - 1) / TPB, TPB, 0, stream>>>(flags);
  lstm_fused<<<256, TPB, 0, stream>>>(x, wih0, whh0, bih0, bhh0,
                                      wih1, whh1, bih1, bhh1, ring, h1b, flags);
  final_linear<<<BTOT, 64, 0, stream>>>(h1b, lin_w, lin_b, out);
}

// Round 6
// 6557.795 us; speedup vs baseline: 1.2148x; 1.1653x over previous
//
#include <hip/hip_runtime.h>
#include <cstddef>
#include <cstdint>

typedef unsigned long long ull;
typedef unsigned short u16;
typedef __attribute__((ext_vector_type(8))) short s8v;   // 8 x bf16 (MFMA A/B frag)
typedef __attribute__((ext_vector_type(4))) float f4v;   // MFMA C/D frag

#define GROUPS 8
#define WPG    32
#define BG     16
#define JS     16
#define TPB    256
#define NT     1024
#define HDIM   512
#define INDIM  17
#define OUTDIM 17
#define BTOT   128
#define RING_D 4

// Cross-WG traffic: relaxed agent-scope atomics (sc1 -> MALL). No fences.
#define AT_LD(p)   __hip_atomic_load((p), __ATOMIC_RELAXED, __HIP_MEMORY_SCOPE_AGENT)
#define AT_ST(p,v) __hip_atomic_store((p), (v), __ATOMIC_RELAXED, __HIP_MEMORY_SCOPE_AGENT)

// ---------------- frag-order tile layout (global) ----------------
// Plane = 16 b x 512 k; u16 idx(k,b) = (k>>5)*512 + ((k>>3)&3)*128 + b*8 + (k&7).
// -> MFMA A-frag (8 consecutive k of one b) is 16B contiguous; a wave's 64
// frags for one k-tile form a contiguous 1KB burst.
#define TILE_U16 8192
#define WIDX(k, b) ((((k) >> 5) * 512) + ((((k) >> 3) & 3) * 128) + ((b) * 8) + ((k) & 7))

// ---------------- workspace ----------------
#define CNT_INTS   (GROUPS * 16)                              // 64B-stride counters
#define RING_OFF   ((size_t)CNT_INTS * 4)
#define RING_U16   ((size_t)RING_D * GROUPS * 2 * TILE_U16)   // h0 ring
#define H1_OFF     (RING_OFF + RING_U16 * 2)
#define H1_U16     ((size_t)2 * GROUPS * 2 * TILE_U16)        // h1 dbuf
#define WS_NEEDED  (H1_OFF + H1_U16 * 2)                      // ~1.6 MB

#define RIDX2(sl, gr, pl)  ((((size_t)(sl) * GROUPS + (gr)) * 2 + (pl)) * TILE_U16)
#define H1IDX2(pp, gr, pl) ((((size_t)(pp) * GROUPS + (gr)) * 2 + (pl)) * TILE_U16)

// ---------------- LDS layout ----------------
// Staged plane: 16 k-blocks x 1088B (q-blocks padded 256->272B: <=2-way banks).
#define LPLANE   17408
#define L_P0H    0
#define L_P0L    (LPLANE)
#define L_P1H    (2 * LPLANE)
#define L_P1L    (3 * LPLANE)
#define L_RED    (4 * LPLANE)            // float[4*8*16*16] = 32 KB
#define LDS_SZ   (L_RED + 32768)         // 102400 B

// ---------------- helpers ----------------
__device__ __forceinline__ u16 f2bf(float f) {
  unsigned int u = __float_as_uint(f);
  u += 0x7FFFu + ((u >> 16) & 1u);
  return (u16)(u >> 16);
}
__device__ __forceinline__ float bf2f(u16 h) {
  return __uint_as_float(((unsigned int)h) << 16);
}
__device__ __forceinline__ float sigm(float x) { return 1.f / (1.f + __expf(-x)); }
__device__ __forceinline__ float tanh_f(float x) { return 2.f / (1.f + __expf(-2.f * x)) - 1.f; }

#define MFMA(a, b, c) __builtin_amdgcn_mfma_f32_16x16x32_bf16((a), (b), (c), 0, 0, 0)

// ---------------- fused 2-layer persistent LSTM ----------------
// 256 WGs (1/CU). Group gr = bid&7: batches [gr*16,gr*16+16); WG wg = bid>>3
// owns j-slice [wg*16,wg*16+16) for both layers.
// Per step: block-cooperative coalesced MALL loads stage the 4 h-planes into
// LDS; wave w then ds_reads only its k-quarter and computes all 4 gates'
// partials (K-split); partials reduced via 32KB LDS exchange.
// Sync: one atomic counter per group (publish +1, poll >= 32*s).
__global__ __launch_bounds__(TPB, 1) void lstm_fused(
    const float* __restrict__ x,
    const float* __restrict__ wih0, const float* __restrict__ whh0,
    const float* __restrict__ bih0, const float* __restrict__ bhh0,
    const float* __restrict__ wih1, const float* __restrict__ whh1,
    const float* __restrict__ bih1, const float* __restrict__ bhh1,
    u16* __restrict__ ring,   // h0 ring [slot4][gr][pl2][frag-order 8192]
    u16* __restrict__ h1b,    // h1 dbuf [pp2][gr][pl2][frag-order 8192]
    int* __restrict__ cnt)    // per-group arrival counters (64B stride)
{
  const int bid  = blockIdx.x;
  const int gr   = bid & 7;
  const int wg   = bid >> 3;
  const int j0   = wg * JS;
  const int tid  = threadIdx.x;
  const int wave = tid >> 6;
  const int lane = tid & 63;
  const int n    = lane & 15;        // A-frag row (batch) / B-frag col (j)
  const int q    = lane >> 4;        // k-sub-quad within a 32-tile
  const int k0   = q * 8;
  const int kw   = wave * 128;       // this wave's k-quarter base

  __shared__ char smem[LDS_SZ];
  float* red = (float*)(smem + L_RED);

  // ---- stationary weights: per wave, 4 gates x 4 k-tiles of its quarter ----
  s8v w0x_h, w0x_l;   // wih0 (K=17): gate = wave, padded single tile
  {
    const float* wr = wih0 + (size_t)(wave * HDIM + j0 + n) * INDIM;
#pragma unroll
    for (int j = 0; j < 8; ++j) {
      int k = k0 + j;
      float v = (k < INDIM) ? wr[k] : 0.f;
      u16 hi = f2bf(v);
      w0x_h[j] = (short)hi;
      w0x_l[j] = (short)f2bf(v - bf2f(hi));
    }
  }
  s8v w0hh[4][4], w0hl[4][4], w1xh[4][4], w1hh[4][4], w1hl[4][4];  // [gate][kt]
#pragma unroll
  for (int g = 0; g < 4; ++g) {
    const size_t row = (size_t)(g * HDIM + j0 + n);
    const float* p0 = whh0 + row * HDIM;
    const float* p1 = wih1 + row * HDIM;
    const float* p2 = whh1 + row * HDIM;
#pragma unroll
    for (int kt = 0; kt < 4; ++kt) {
#pragma unroll
      for (int j = 0; j < 8; ++j) {
        int k = kw + kt * 32 + k0 + j;
        float v0 = p0[k], v2 = p2[k];
        u16 h0q = f2bf(v0), h2q = f2bf(v2);
        w0hh[g][kt][j] = (short)h0q;
        w0hl[g][kt][j] = (short)f2bf(v0 - bf2f(h0q));
        w1xh[g][kt][j] = (short)f2bf(p1[k]);
        w1hh[g][kt][j] = (short)h2q;
        w1hl[g][kt][j] = (short)f2bf(v2 - bf2f(h2q));
      }
    }
  }
  const int b_l = tid >> 4, j_l = tid & 15, jg = j0 + j_l;
  float bL0[4], bL1[4];
#pragma unroll
  for (int g = 0; g < 4; ++g) {
    bL0[g] = bih0[g * HDIM + jg] + bhh0[g * HDIM + jg];
    bL1[g] = bih1[g * HDIM + jg] + bhh1[g * HDIM + jg];
  }

  float c0 = 0.f, c1 = 0.f;
  const int wofs = WIDX(jg, b_l);   // this thread's h slot (frag-order)

  // ---- init h0 ring slot0 = 0, h1 parity0 = 0; publish step-0 ----
  AT_ST(&ring[RIDX2(0, gr, 0) + wofs], (u16)0);
  AT_ST(&ring[RIDX2(0, gr, 1) + wofs], (u16)0);
  AT_ST(&h1b[H1IDX2(0, gr, 0) + wofs], (u16)0);
  AT_ST(&h1b[H1IDX2(0, gr, 1) + wofs], (u16)0);
  __syncthreads();  // drains init stores
  if (tid == 0) (void)__hip_atomic_fetch_add(&cnt[gr * 16], 1, __ATOMIC_RELAXED,
                                             __HIP_MEMORY_SCOPE_AGENT);

  const f4v z = {0.f, 0.f, 0.f, 0.f};
  // staging address pieces: linear ull chunk lc -> padded LDS offset
  int lofs[8];
#pragma unroll
  for (int r = 0; r < 8; ++r) {
    int lc = r * 256 + tid;                 // 0..2047 per plane
    int blk = lc >> 7, rem = lc & 127;
    lofs[r] = blk * 1088 + (rem >> 5) * 272 + ((rem >> 1) & 15) * 16 + (rem & 1) * 8;
  }

  for (int s = 1; s <= NT + 1; ++s) {
    const bool doL0 = (s <= NT);
    const bool doL1 = (s >= 2);

    // L0 x-part for gate `wave` (no peer dependency): before the wait
    f4v xacc = z;
    if (doL0) {
      const int t = s - 1;
      const float* xr = x + ((size_t)(gr * BG + n) * NT + t) * INDIM;
      s8v axh, axl;
#pragma unroll
      for (int j = 0; j < 8; ++j) {
        int k = k0 + j;
        float v = (k < INDIM) ? xr[k] : 0.f;
        u16 hi = f2bf(v);
        axh[j] = (short)hi;
        axl[j] = (short)f2bf(v - bf2f(hi));
      }
      xacc = MFMA(axh, w0x_h, xacc);
      xacc = MFMA(axl, w0x_h, xacc);
      xacc = MFMA(axh, w0x_l, xacc);
    }

    // wait: all 32 group peers published step s-1 (counter >= 32*s)
    if (tid == 0) {
      const int* cp = &cnt[gr * 16];
      const int tgt = 32 * s;
      while (AT_LD(cp) < tgt) __builtin_amdgcn_s_sleep(1);
    }
    __syncthreads();   // [B1]

    // ---- stage 4 h-planes: MALL -> LDS, block-coalesced linear copy ----
    {
      const int sl  = (s - 1) & (RING_D - 1);
      const int pp1 = s & 1;   // h1[s-2] parity (garbage at s=1, unused)
      const ull* g0h = (const ull*)(ring + RIDX2(sl, gr, 0));
      const ull* g0l = (const ull*)(ring + RIDX2(sl, gr, 1));
      const ull* g1h = (const ull*)(h1b + H1IDX2(pp1, gr, 0));
      const ull* g1l = (const ull*)(h1b + H1IDX2(pp1, gr, 1));
      ull v0h[8], v0l[8], v1h[8], v1l[8];
#pragma unroll
      for (int r = 0; r < 8; ++r) {
        int lc = r * 256 + tid;
        v0h[r] = AT_LD(g0h + lc);
        v0l[r] = AT_LD(g0l + lc);
        v1h[r] = AT_LD(g1h + lc);
        v1l[r] = AT_LD(g1l + lc);
      }
#pragma unroll
      for (int r = 0; r < 8; ++r) {
        *(ull*)(smem + L_P0H + lofs[r]) = v0h[r];
        *(ull*)(smem + L_P0L + lofs[r]) = v0l[r];
        *(ull*)(smem + L_P1H + lofs[r]) = v1h[r];
        *(ull*)(smem + L_P1L + lofs[r]) = v1l[r];
      }
    }
    __syncthreads();   // [B2] stage ready

    // ---- frag reads (this wave's k-quarter) + MFMA partials, all 4 gates ----
    s8v a0h[4], a0l[4], a1h[4], a1l[4];
#pragma unroll
    for (int kt = 0; kt < 4; ++kt) {
      int off = (wave * 4 + kt) * 1088 + q * 272 + n * 16;
      a0h[kt] = *(const s8v*)(smem + L_P0H + off);
      a0l[kt] = *(const s8v*)(smem + L_P0L + off);
      a1h[kt] = *(const s8v*)(smem + L_P1H + off);
      a1l[kt] = *(const s8v*)(smem + L_P1L + off);
    }
    f4v accL0[4] = {z, z, z, z}, accL1[4] = {z, z, z, z};
#pragma unroll
    for (int kt = 0; kt < 4; ++kt)
#pragma unroll
      for (int g = 0; g < 4; ++g) {
        accL0[g] = MFMA(a0h[kt], w0hh[g][kt], accL0[g]);
        accL0[g] = MFMA(a0l[kt], w0hh[g][kt], accL0[g]);
        accL0[g] = MFMA(a0h[kt], w0hl[g][kt], accL0[g]);
        accL1[g] = MFMA(a0h[kt], w1xh[g][kt], accL1[g]);   // L1 x-part shares h0 tile
        accL1[g] = MFMA(a0l[kt], w1xh[g][kt], accL1[g]);
      }
#pragma unroll
    for (int kt = 0; kt < 4; ++kt)
#pragma unroll
      for (int g = 0; g < 4; ++g) {
        accL1[g] = MFMA(a1h[kt], w1hh[g][kt], accL1[g]);
        accL1[g] = MFMA(a1l[kt], w1hh[g][kt], accL1[g]);
        accL1[g] = MFMA(a1h[kt], w1hl[g][kt], accL1[g]);
      }
    accL0[wave] += xacc;

    // ---- write partials: [wave][lg][col n][row16], XOR-swizzled b128 ----
#pragma unroll
    for (int lg = 0; lg < 8; ++lg) {
      const f4v a = (lg < 4) ? accL0[lg] : accL1[lg - 4];
      int base = ((wave * 8 + lg) * 16 + n) * 16;
      int idx = (base + ((q * 4) ^ ((n & 3) << 2))) ^ ((n & 4) << 2);
      *(f4v*)&red[idx] = a;
    }
    __syncthreads();   // [B3] partials ready

    // ---- reduce 4 wave-partials + bias, elementwise update ----
    if (doL0) {
      float p[4];
#pragma unroll
      for (int g = 0; g < 4; ++g) {
        float t = bL0[g];
#pragma unroll
        for (int w = 0; w < 4; ++w) {
          int base = ((w * 8 + g) * 16 + j_l) * 16;
          int idx = (base + (b_l ^ ((j_l & 3) << 2))) ^ ((j_l & 4) << 2);
          t += red[idx];
        }
        p[g] = t;
      }
      float ig = sigm(p[0]), fg = sigm(p[1]), og = sigm(p[3]), gg = tanh_f(p[2]);
      c0 = fg * c0 + ig * gg;
      float h = og * tanh_f(c0);
      u16 hh = f2bf(h), hl = f2bf(h - bf2f(hh));
      int so = s & (RING_D - 1);
      AT_ST(&ring[RIDX2(so, gr, 0) + wofs], hh);
      AT_ST(&ring[RIDX2(so, gr, 1) + wofs], hl);
    }
    if (doL1) {
      float p[4];
#pragma unroll
      for (int g = 0; g < 4; ++g) {
        float t = bL1[g];
#pragma unroll
        for (int w = 0; w < 4; ++w) {
          int base = ((w * 8 + (4 + g)) * 16 + j_l) * 16;
          int idx = (base + (b_l ^ ((j_l & 3) << 2))) ^ ((j_l & 4) << 2);
          t += red[idx];
        }
        p[g] = t;
      }
      float ig = sigm(p[0]), fg = sigm(p[1]), og = sigm(p[3]), gg = tanh_f(p[2]);
      c1 = fg * c1 + ig * gg;
      float h = og * tanh_f(c1);
      u16 hh = f2bf(h), hl = f2bf(h - bf2f(hh));
      int pw = (s - 1) & 1;
      AT_ST(&h1b[H1IDX2(pw, gr, 0) + wofs], hh);
      AT_ST(&h1b[H1IDX2(pw, gr, 1) + wofs], hl);
    }
    __syncthreads();   // [B4] drains h stores; guards LDS reuse
    if (doL0 && tid == 0)
      (void)__hip_atomic_fetch_add(&cnt[gr * 16], 1, __ATOMIC_RELAXED,
                                   __HIP_MEMORY_SCOPE_AGENT);
  }
}

// ---------------- final linear: out = h1[NT] @ lin_w^T + lin_b ----------------
__global__ void final_linear(const u16* __restrict__ h1b,
                             const float* __restrict__ lin_w,
                             const float* __restrict__ lin_b,
                             float* __restrict__ out) {
  int b = blockIdx.x, o = threadIdx.x;
  int gr = b >> 4, b_l = b & 15;
  if (o < OUTDIM) {
    float acc = lin_b[o];
    const u16* ph = h1b + H1IDX2(0, gr, 0);  // h1[1024]: parity 0
    const u16* pl = h1b + H1IDX2(0, gr, 1);
    for (int j = 0; j < HDIM; ++j) {
      int idx = WIDX(j, b_l);
      float h = bf2f(ph[idx]) + bf2f(pl[idx]);
      acc += h * lin_w[(size_t)o * HDIM + j];
    }
    out[b * OUTDIM + o] = acc;
  }
}

__global__ void init_cnt(int* __restrict__ cnt) {
  int i = blockIdx.x * TPB + threadIdx.x;
  if (i < CNT_INTS) cnt[i] = 0;
}

__global__ void sentinel_kernel(float* __restrict__ out, int nv) {
  int i = blockIdx.x * TPB + threadIdx.x;
  if (i < nv) out[i] = 1e30f;
}

extern "C" void kernel_launch(void* const* d_in, const int* in_sizes, int n_in,
                              void* d_out, int out_size, void* d_ws, size_t ws_size,
                              hipStream_t stream) {
  const float* x     = (const float*)d_in[0];
  const float* wih0  = (const float*)d_in[1];
  const float* whh0  = (const float*)d_in[2];
  const float* bih0  = (const float*)d_in[3];
  const float* bhh0  = (const float*)d_in[4];
  const float* wih1  = (const float*)d_in[5];
  const float* whh1  = (const float*)d_in[6];
  const float* bih1  = (const float*)d_in[7];
  const float* bhh1  = (const float*)d_in[8];
  const float* lin_w = (const float*)d_in[9];
  const float* lin_b = (const float*)d_in[10];
  float* out = (float*)d_out;
  char* ws = (char*)d_ws;

  if (ws_size < WS_NEEDED) {
    sentinel_kernel<<<(out_size + TPB - 1) / TPB, TPB, 0, stream>>>(out, out_size);
    return;
  }

  int* cnt  = (int*)ws;
  u16* ring = (u16*)(ws + RING_OFF);
  u16* h1b  = (u16*)(ws + H1_OFF);

  init_cnt<<<1, TPB, 0, stream>>>(cnt);
  lstm_fused<<<256, TPB, 0, stream>>>(x, wih0, whh0, bih0, bhh0,
                                      wih1, whh1, bih1, bhh1, ring, h1b, cnt);
  final_linear<<<BTOT, 64, 0, stream>>>(h1b, lin_w, lin_b, out);
}

// Round 7
// 4993.160 us; speedup vs baseline: 1.5955x; 1.3134x over previous
//
#include <hip/hip_runtime.h>
#include <cstddef>
#include <cstdint>

typedef unsigned long long ull;
typedef unsigned short u16;
typedef __attribute__((ext_vector_type(8))) short s8v;   // 8 x bf16 (MFMA A/B frag)
typedef __attribute__((ext_vector_type(4))) float f4v;   // MFMA C/D frag

#define GROUPS 8
#define BG     16
#define JS     16
#define TPB    256
#define NT     1024
#define HDIM   512
#define INDIM  17
#define OUTDIM 17
#define BTOT   128

// Cross-WG traffic: relaxed agent-scope atomics (sc1 -> MALL). No fences.
#define AT_LD(p)   __hip_atomic_load((p), __ATOMIC_RELAXED, __HIP_MEMORY_SCOPE_AGENT)
#define AT_ST(p,v) __hip_atomic_store((p), (v), __ATOMIC_RELAXED, __HIP_MEMORY_SCOPE_AGENT)

// frag-order plane: 16b x 512k; u16 idx(k,b) = (k>>5)*512 + ((k>>3)&3)*128 + b*8 + (k&7)
// -> wave frag reads for one k-tile form a contiguous 1KB burst.
#define TILE_U16 8192
#define WIDX(k, b) ((((k) >> 5) * 512) + ((((k) >> 3) & 3) * 128) + ((b) * 8) + ((k) & 7))

// ---------------- workspace ----------------
#define FA_OFF     ((size_t)0)
#define FB_OFF     ((size_t)16384)
#define RA_OFF     ((size_t)32768)
#define RING_BYTES ((size_t)4 * GROUPS * 2 * TILE_U16 * 2)    // 4-slot ring, 1 MB
#define RB_OFF     (RA_OFF + RING_BYTES)
#define WS_NEEDED  (RB_OFF + RING_BYTES)                      // ~2.1 MB
#define RIX(sl, gr, pl) ((((size_t)(sl) * GROUPS + (gr)) * 2 + (pl)) * TILE_U16)

// ---------------- LDS layout ----------------
// h0 stage ring: 3 slots x 2 planes x 16384B = 98304
// h1 stage:      2 planes x 16384B           = 32768
// exchange A/B:  4KB each                    = 8192
// control ints                               = 64
#define L_H0   0
#define L_H1   98304
#define L_EXA  131072
#define L_EXB  135168
#define L_CTL  139264
#define LDS_SZ 139328
// ctl indices: 0=ctrA 1=ctrB 2=go0 3=go1 4..6=stage_ready[3]

__device__ __forceinline__ u16 f2bf(float f) {
  unsigned int u = __float_as_uint(f);
  u += 0x7FFFu + ((u >> 16) & 1u);
  return (u16)(u >> 16);
}
__device__ __forceinline__ float bf2f(u16 h) {
  return __uint_as_float(((unsigned int)h) << 16);
}
__device__ __forceinline__ float sigm(float x) { return 1.f / (1.f + __expf(-x)); }
__device__ __forceinline__ float tanh_f(float x) { return 2.f / (1.f + __expf(-2.f * x)) - 1.f; }

#define MFMA(a, b, c) __builtin_amdgcn_mfma_f32_16x16x32_bf16((a), (b), (c), 0, 0, 0)

// 2-wave pair barrier via LDS monotonic counter (lane0 adds, all spin)
__device__ __forceinline__ void pbar(int* c, int& nbar, int lane) {
  ++nbar;
  if (lane == 0)
    (void)__hip_atomic_fetch_add(c, 1, __ATOMIC_RELEASE, __HIP_MEMORY_SCOPE_WORKGROUP);
  while (__hip_atomic_load(c, __ATOMIC_ACQUIRE, __HIP_MEMORY_SCOPE_WORKGROUP) < 2 * nbar) {}
}

// ---------------- fused 2-layer persistent LSTM, wave-specialized ----------------
// 256 WGs (1/CU). gr = bid&7 owns batches [gr*16,..); wg = bid>>3 owns j-slice.
// Waves 0-1 = L0 pipeline (2 gates each, full K).  Waves 2-3 = L1 pipeline.
// L0 step s: stage h0[s-1] (global ringA -> LDS slot (s-1)%3), MFMA, elementwise,
//   store ringA slot s%4, publish flagA=s+1.  Also publishes the LDS stage to L1
//   via stage_ready (h0-state[s-1] = L1 step s-1's x-input).
// L1 step t: stage h1[t-1] (ringB), MFMA over LDS h0 slot t%3 + h1, elementwise,
//   store ringB slot t%4, publish flagB=t+1.
// Poll: one 64-lane gather: lanes<32 flagA>=s, lanes>=32 flagB>=s-3 (LDS-slot
// clobber back-pressure). Pair-internal sync: LDS barriers; publish after
// explicit s_waitcnt vmcnt(0). No __syncthreads in the loop.
__global__ __launch_bounds__(TPB, 1) void lstm_fused(
    const float* __restrict__ x,
    const float* __restrict__ wih0, const float* __restrict__ whh0,
    const float* __restrict__ bih0, const float* __restrict__ bhh0,
    const float* __restrict__ wih1, const float* __restrict__ whh1,
    const float* __restrict__ bih1, const float* __restrict__ bhh1,
    u16* __restrict__ ringA, u16* __restrict__ ringB,
    int* __restrict__ flagsA, int* __restrict__ flagsB)
{
  const int bid  = blockIdx.x;
  const int gr   = bid & 7;
  const int wg   = bid >> 3;
  const int j0   = wg * JS;
  const int tid  = threadIdx.x;
  const int wave = tid >> 6;
  const int lane = tid & 63;
  const int n    = lane & 15;        // A-frag row (batch) / B-frag col (j)
  const int q    = lane >> 4;        // k-sub-quad
  const int k0   = q * 8;

  __shared__ __align__(16) char smem[LDS_SZ];
  int* ctl = (int*)(smem + L_CTL);
  float* exgA = (float*)(smem + L_EXA);
  float* exgB = (float*)(smem + L_EXB);

  if (tid < 8) ctl[tid] = 0;

  // ---- init ring slot 0 = zeros (own slice), then publish flags = 1 ----
  {
    int b_l = tid >> 4, j_l = tid & 15, jg = j0 + j_l;
    int wo = WIDX(jg, b_l);
    AT_ST(&ringA[RIX(0, gr, 0) + wo], (u16)0);
    AT_ST(&ringA[RIX(0, gr, 1) + wo], (u16)0);
    AT_ST(&ringB[RIX(0, gr, 0) + wo], (u16)0);
    AT_ST(&ringB[RIX(0, gr, 1) + wo], (u16)0);
  }
  __syncthreads();  // full drain (vmcnt0+lgkmcnt0) before flags; only barrier used
  if (wave == 0 && lane == 0) AT_ST(flagsA + bid * 16, 1);
  if (wave == 2 && lane == 0) AT_ST(flagsB + bid * 16, 1);

  const f4v z = {0.f, 0.f, 0.f, 0.f};
  const int p  = (wave & 1) * 64 + lane;  // pair-tid 0..127
  const int jq = p & 15, b0 = p >> 4;     // cells (b0,jq) and (b0+8,jq)
  const int jg = j0 + jq;
  const int wo0 = WIDX(jg, b0), wo1 = WIDX(jg, b0 + 8);

  if (wave < 2) {
    // ================= L0 pipeline (waves 0,1) =================
    const int g0 = wave * 2;  // gates g0, g0+1 (full K)
    s8v wx_h[2], wx_l[2];
#pragma unroll
    for (int i = 0; i < 2; ++i) {
      const float* wr = wih0 + (size_t)((g0 + i) * HDIM + j0 + n) * INDIM;
#pragma unroll
      for (int j = 0; j < 8; ++j) {
        int k = k0 + j;
        float v = (k < INDIM) ? wr[k] : 0.f;
        u16 hi = f2bf(v);
        wx_h[i][j] = (short)hi;
        wx_l[i][j] = (short)f2bf(v - bf2f(hi));
      }
    }
    s8v wh_h[2][16], wh_l[2][16];
#pragma unroll
    for (int i = 0; i < 2; ++i) {
      const float* wr = whh0 + (size_t)((g0 + i) * HDIM + j0 + n) * HDIM;
#pragma unroll
      for (int kt = 0; kt < 16; ++kt)
#pragma unroll
        for (int j = 0; j < 8; ++j) {
          float v = wr[kt * 32 + k0 + j];
          u16 hi = f2bf(v);
          wh_h[i][kt][j] = (short)hi;
          wh_l[i][kt][j] = (short)f2bf(v - bf2f(hi));
        }
    }
    float bias[4];
#pragma unroll
    for (int g = 0; g < 4; ++g) bias[g] = bih0[g * HDIM + jg] + bhh0[g * HDIM + jg];
    float c0a = 0.f, c0b = 0.f;
    int nbar = 0;

    for (int s = 1; s <= NT + 1; ++s) {
      // x-part (no peer dependency): before the wait
      f4v xa[2] = {z, z};
      if (s <= NT) {
        const float* xr = x + ((size_t)(gr * BG + n) * NT + (s - 1)) * INDIM;
        s8v axh, axl;
#pragma unroll
        for (int j = 0; j < 8; ++j) {
          int k = k0 + j;
          float v = (k < INDIM) ? xr[k] : 0.f;
          u16 hi = f2bf(v);
          axh[j] = (short)hi;
          axl[j] = (short)f2bf(v - bf2f(hi));
        }
#pragma unroll
        for (int i = 0; i < 2; ++i) {
          xa[i] = MFMA(axh, wx_h[i], xa[i]);
          xa[i] = MFMA(axl, wx_h[i], xa[i]);
          xa[i] = MFMA(axh, wx_l[i], xa[i]);
        }
      }
      // poll: lanes<32 peer flagA >= s; lanes>=32 flagB >= s-3 (LDS-slot guard)
      if (wave == 0) {
        const int* pp = (lane < 32) ? (flagsA + (lane * 8 + gr) * 16)
                                    : (flagsB + ((lane & 31) * 8 + gr) * 16);
        const int tgt = (lane < 32) ? s : s - 3;
        while (__ballot(AT_LD(pp) >= tgt) != ~0ULL) __builtin_amdgcn_s_sleep(1);
        __hip_atomic_store(&ctl[2], s, __ATOMIC_RELEASE, __HIP_MEMORY_SCOPE_WORKGROUP);
      } else {
        while (__hip_atomic_load(&ctl[2], __ATOMIC_ACQUIRE, __HIP_MEMORY_SCOPE_WORKGROUP) < s) {}
      }
      // stage h0[s-1]: ringA slot (s-1)&3 -> LDS slot (s-1)%3 (W0 hi, W1 lo)
      const int sl3 = (s - 1) % 3;
      {
        const ull* src = (const ull*)(ringA + RIX((s - 1) & 3, gr, wave));
        char* dst = smem + L_H0 + (sl3 * 2 + wave) * 16384;
#pragma unroll
        for (int r = 0; r < 32; r += 16) {
          ull v[16];
#pragma unroll
          for (int i = 0; i < 16; ++i) v[i] = AT_LD(src + (r + i) * 64 + lane);
#pragma unroll
          for (int i = 0; i < 16; ++i) *(ull*)(dst + ((r + i) * 64 + lane) * 8) = v[i];
        }
      }
      pbar(&ctl[0], nbar, lane);                              // P1: stage visible
      if (wave == 0 && lane == 0)
        __hip_atomic_store(&ctl[4 + sl3], s - 1, __ATOMIC_RELEASE,
                           __HIP_MEMORY_SCOPE_WORKGROUP);
      if (s == NT + 1) break;  // tail step only feeds L1's last x-input

      // K-loop: frag reads from LDS stage + 96 MFMA (2 gates x 16kt x 3 planes)
      const char* sh = smem + L_H0 + (sl3 * 2 + 0) * 16384;
      const char* sl = smem + L_H0 + (sl3 * 2 + 1) * 16384;
      f4v cHH[2] = {z, z}, cLH[2] = {z, z}, cHL[2] = {z, z};
#pragma unroll
      for (int kt = 0; kt < 16; ++kt) {
        s8v ah = *(const s8v*)(sh + kt * 1024 + q * 256 + n * 16);
        s8v al = *(const s8v*)(sl + kt * 1024 + q * 256 + n * 16);
#pragma unroll
        for (int i = 0; i < 2; ++i) {
          cHH[i] = MFMA(ah, wh_h[i][kt], cHH[i]);
          cLH[i] = MFMA(al, wh_h[i][kt], cLH[i]);
          cHL[i] = MFMA(ah, wh_l[i][kt], cHL[i]);
        }
      }
#pragma unroll
      for (int i = 0; i < 2; ++i) {
        f4v e = xa[i] + cHH[i] + cLH[i] + cHL[i];
#pragma unroll
        for (int r = 0; r < 4; ++r)
          exgA[(g0 + i) * 256 + (q * 4 + r) * 16 + n] = e[r];
      }
      pbar(&ctl[0], nbar, lane);                              // P2: preacts ready
      // elementwise: 2 cells per thread
      float pr0[4], pr1[4];
#pragma unroll
      for (int g = 0; g < 4; ++g) {
        pr0[g] = exgA[g * 256 + b0 * 16 + jq] + bias[g];
        pr1[g] = exgA[g * 256 + (b0 + 8) * 16 + jq] + bias[g];
      }
      {
        float ig = sigm(pr0[0]), fg = sigm(pr0[1]), gg = tanh_f(pr0[2]), og = sigm(pr0[3]);
        c0a = fg * c0a + ig * gg;
        float h = og * tanh_f(c0a);
        u16 hh = f2bf(h), hl = f2bf(h - bf2f(hh));
        AT_ST(&ringA[RIX(s & 3, gr, 0) + wo0], hh);
        AT_ST(&ringA[RIX(s & 3, gr, 1) + wo0], hl);
      }
      {
        float ig = sigm(pr1[0]), fg = sigm(pr1[1]), gg = tanh_f(pr1[2]), og = sigm(pr1[3]);
        c0b = fg * c0b + ig * gg;
        float h = og * tanh_f(c0b);
        u16 hh = f2bf(h), hl = f2bf(h - bf2f(hh));
        AT_ST(&ringA[RIX(s & 3, gr, 0) + wo1], hh);
        AT_ST(&ringA[RIX(s & 3, gr, 1) + wo1], hl);
      }
      __asm__ volatile("s_waitcnt vmcnt(0)" ::: "memory");    // drain own stores
      pbar(&ctl[0], nbar, lane);                              // P3: pair drained
      if (wave == 0 && lane == 0) AT_ST(flagsA + bid * 16, s + 1);
    }
  } else {
    // ================= L1 pipeline (waves 2,3) =================
    const int wv = wave - 2;
    const int g0 = wv * 2;  // gates g0, g0+1 (full K); wih1 & whh1 hi-only
    s8v w1x[2][16], w1h[2][16];
#pragma unroll
    for (int i = 0; i < 2; ++i) {
      const float* p1 = wih1 + (size_t)((g0 + i) * HDIM + j0 + n) * HDIM;
      const float* p2 = whh1 + (size_t)((g0 + i) * HDIM + j0 + n) * HDIM;
#pragma unroll
      for (int kt = 0; kt < 16; ++kt)
#pragma unroll
        for (int j = 0; j < 8; ++j) {
          w1x[i][kt][j] = (short)f2bf(p1[kt * 32 + k0 + j]);
          w1h[i][kt][j] = (short)f2bf(p2[kt * 32 + k0 + j]);
        }
    }
    float bias[4];
#pragma unroll
    for (int g = 0; g < 4; ++g) bias[g] = bih1[g * HDIM + jg] + bhh1[g * HDIM + jg];
    float c1a = 0.f, c1b = 0.f;
    int nbar = 0;

    for (int t = 1; t <= NT; ++t) {
      // poll: peers' flagB >= t (h1[t-1] published)
      if (wave == 2) {
        const int* pp = flagsB + ((lane & 31) * 8 + gr) * 16;
        while (__ballot(AT_LD(pp) >= t) != ~0ULL) __builtin_amdgcn_s_sleep(1);
        __hip_atomic_store(&ctl[3], t, __ATOMIC_RELEASE, __HIP_MEMORY_SCOPE_WORKGROUP);
      } else {
        while (__hip_atomic_load(&ctl[3], __ATOMIC_ACQUIRE, __HIP_MEMORY_SCOPE_WORKGROUP) < t) {}
      }
      // stage h1[t-1]: ringB slot (t-1)&3 -> LDS (W2 hi, W3 lo)
      {
        const ull* src = (const ull*)(ringB + RIX((t - 1) & 3, gr, wv));
        char* dst = smem + L_H1 + wv * 16384;
#pragma unroll
        for (int r = 0; r < 32; r += 16) {
          ull v[16];
#pragma unroll
          for (int i = 0; i < 16; ++i) v[i] = AT_LD(src + (r + i) * 64 + lane);
#pragma unroll
          for (int i = 0; i < 16; ++i) *(ull*)(dst + ((r + i) * 64 + lane) * 8) = v[i];
        }
      }
      pbar(&ctl[1], nbar, lane);                              // Q1: h1 staged
      // K-loop B: h1 recurrence (hi+lo activations x hi weights)
      const char* th = smem + L_H1;
      const char* tl = smem + L_H1 + 16384;
      f4v dHH[2] = {z, z}, dLH[2] = {z, z};
#pragma unroll
      for (int kt = 0; kt < 16; ++kt) {
        s8v ah = *(const s8v*)(th + kt * 1024 + q * 256 + n * 16);
        s8v al = *(const s8v*)(tl + kt * 1024 + q * 256 + n * 16);
#pragma unroll
        for (int i = 0; i < 2; ++i) {
          dHH[i] = MFMA(ah, w1h[i][kt], dHH[i]);
          dLH[i] = MFMA(al, w1h[i][kt], dLH[i]);
        }
      }
      // wait for local L0's LDS stage of h0-state[t] (= our x-input y0[t-1])
      const int sl3 = t % 3;
      while (__hip_atomic_load(&ctl[4 + sl3], __ATOMIC_ACQUIRE,
                               __HIP_MEMORY_SCOPE_WORKGROUP) < t) {}
      const char* sh = smem + L_H0 + (sl3 * 2 + 0) * 16384;
      const char* sl = smem + L_H0 + (sl3 * 2 + 1) * 16384;
      f4v eHH[2] = {z, z}, eLH[2] = {z, z};
#pragma unroll
      for (int kt = 0; kt < 16; ++kt) {
        s8v ah = *(const s8v*)(sh + kt * 1024 + q * 256 + n * 16);
        s8v al = *(const s8v*)(sl + kt * 1024 + q * 256 + n * 16);
#pragma unroll
        for (int i = 0; i < 2; ++i) {
          eHH[i] = MFMA(ah, w1x[i][kt], eHH[i]);
          eLH[i] = MFMA(al, w1x[i][kt], eLH[i]);
        }
      }
#pragma unroll
      for (int i = 0; i < 2; ++i) {
        f4v e = dHH[i] + dLH[i] + eHH[i] + eLH[i];
#pragma unroll
        for (int r = 0; r < 4; ++r)
          exgB[(g0 + i) * 256 + (q * 4 + r) * 16 + n] = e[r];
      }
      pbar(&ctl[1], nbar, lane);                              // Q2: preacts ready
      float pr0[4], pr1[4];
#pragma unroll
      for (int g = 0; g < 4; ++g) {
        pr0[g] = exgB[g * 256 + b0 * 16 + jq] + bias[g];
        pr1[g] = exgB[g * 256 + (b0 + 8) * 16 + jq] + bias[g];
      }
      {
        float ig = sigm(pr0[0]), fg = sigm(pr0[1]), gg = tanh_f(pr0[2]), og = sigm(pr0[3]);
        c1a = fg * c1a + ig * gg;
        float h = og * tanh_f(c1a);
        u16 hh = f2bf(h), hl = f2bf(h - bf2f(hh));
        AT_ST(&ringB[RIX(t & 3, gr, 0) + wo0], hh);
        AT_ST(&ringB[RIX(t & 3, gr, 1) + wo0], hl);
      }
      {
        float ig = sigm(pr1[0]), fg = sigm(pr1[1]), gg = tanh_f(pr1[2]), og = sigm(pr1[3]);
        c1b = fg * c1b + ig * gg;
        float h = og * tanh_f(c1b);
        u16 hh = f2bf(h), hl = f2bf(h - bf2f(hh));
        AT_ST(&ringB[RIX(t & 3, gr, 0) + wo1], hh);
        AT_ST(&ringB[RIX(t & 3, gr, 1) + wo1], hl);
      }
      __asm__ volatile("s_waitcnt vmcnt(0)" ::: "memory");
      pbar(&ctl[1], nbar, lane);                              // Q3: pair drained
      if (wave == 2 && lane == 0) AT_ST(flagsB + bid * 16, t + 1);
    }
  }
}

// ---------------- final linear: out = h1[NT] @ lin_w^T + lin_b ----------------
__global__ void final_linear(const u16* __restrict__ ringB,
                             const float* __restrict__ lin_w,
                             const float* __restrict__ lin_b,
                             float* __restrict__ out) {
  int b = blockIdx.x, o = threadIdx.x;
  int gr = b >> 4, b_l = b & 15;
  if (o < OUTDIM) {
    float acc = lin_b[o];
    const u16* ph = ringB + RIX(NT & 3, gr, 0);   // NT%4 == 0
    const u16* pl = ringB + RIX(NT & 3, gr, 1);
    for (int j = 0; j < HDIM; ++j) {
      int idx = WIDX(j, b_l);
      float h = bf2f(ph[idx]) + bf2f(pl[idx]);
      acc += h * lin_w[(size_t)o * HDIM + j];
    }
    out[b * OUTDIM + o] = acc;
  }
}

__global__ void init_flags(int* __restrict__ f) {
  int i = blockIdx.x * TPB + threadIdx.x;
  if (i < 2 * 4096) f[i] = 0;   // flagsA + flagsB contiguous
}

__global__ void sentinel_kernel(float* __restrict__ out, int nv) {
  int i = blockIdx.x * TPB + threadIdx.x;
  if (i < nv) out[i] = 1e30f;
}

extern "C" void kernel_launch(void* const* d_in, const int* in_sizes, int n_in,
                              void* d_out, int out_size, void* d_ws, size_t ws_size,
                              hipStream_t stream) {
  (void)in_sizes; (void)n_in;
  const float* x     = (const float*)d_in[0];
  const float* wih0  = (const float*)d_in[1];
  const float* whh0  = (const float*)d_in[2];
  const float* bih0  = (const float*)d_in[3];
  const float* bhh0  = (const float*)d_in[4];
  const float* wih1  = (const float*)d_in[5];
  const float* whh1  = (const float*)d_in[6];
  const float* bih1  = (const float*)d_in[7];
  const float* bhh1  = (const float*)d_in[8];
  const float* lin_w = (const float*)d_in[9];
  const float* lin_b = (const float*)d_in[10];
  float* out = (float*)d_out;
  char* ws = (char*)d_ws;

  if (ws_size < WS_NEEDED) {
    sentinel_kernel<<<(out_size + TPB - 1) / TPB, TPB, 0, stream>>>(out, out_size);
    return;
  }

  int* flagsA = (int*)(ws + FA_OFF);
  int* flagsB = (int*)(ws + FB_OFF);
  u16* ringA  = (u16*)(ws + RA_OFF);
  u16* ringB  = (u16*)(ws + RB_OFF);

  init_flags<<<(2 * 4096 + TPB - 1) / TPB, TPB, 0, stream>>>(flagsA);
  lstm_fused<<<256, TPB, 0, stream>>>(x, wih0, whh0, bih0, bhh0,
                                      wih1, whh1, bih1, bhh1,
                                      ringA, ringB, flagsA, flagsB);
  final_linear<<<BTOT, 64, 0, stream>>>(ringB, lin_w, lin_b, out);
}